// Round 12
// baseline (143.414 us; speedup 1.0000x reference)
//
#include <hip/hip_runtime.h>

// q pre-scaled by SCALE*log2(e) at pack time -> logits are exp2-ready.
// Clamp(+-80) dropped: post-scale logits ~N(0,1); 80 sigma unreachable.
#define S2F (0.35355339059327373f * 1.4426950408889634f)

using h2 = decltype(__builtin_amdgcn_cvt_pkrtz(0.0f, 0.0f));
typedef _Float16 half8 __attribute__((ext_vector_type(8)));
typedef float f32x4 __attribute__((ext_vector_type(4)));

static __device__ __forceinline__ h2 u2h(unsigned u) { return __builtin_bit_cast(h2, u); }
static __device__ __forceinline__ unsigned pkf16(float a, float b) {
  return __builtin_bit_cast(unsigned, __builtin_amdgcn_cvt_pkrtz(a, b));
}
static __device__ __forceinline__ half8 u4h8(uint4 u) { return __builtin_bit_cast(half8, u); }

// ws layout (u32 offsets):
//   q4  [2][4096][4]u  @ 0       8 f16 o-values per n, PRE-SCALED by S2F
//   k4  [2][4096][4]u  @ 32768
//   v16 [2][64][2048]u @ 65536   f16 n-pairs
//   lsv2 [2][4096] f32 @ 327680  -log2(sum_m exp2(q'.k))
//   bar  [2]u          @ 335872  barrier counters (memset to 0 per launch)

// Lightweight grid barrier: 1 device-scope atomic + backoff spin (NOT cg
// grid.sync — r8 post-mortem: cg cost ~70us/sync). All 256 blocks resident
// by construction (LDS 72KB -> 2 blocks/CU capacity, grid=256=CU count).
static __device__ __forceinline__ void gbar(unsigned* cnt, unsigned target) {
  __syncthreads();
  if (threadIdx.x == 0) {
    __threadfence();                    // release: flush our writes device-wide
    atomicAdd(cnt, 1u);                 // device scope by default
    while (__hip_atomic_load(cnt, __ATOMIC_RELAXED, __HIP_MEMORY_SCOPE_AGENT) < target)
      __builtin_amdgcn_s_sleep(16);     // ~1k cy backoff: don't hammer the line
  }
  __syncthreads();
  __threadfence();                      // acquire: invalidate stale cache lines
}

// One dispatch, 256 blocks x 512 threads.
// Phase 1 QKV: block=(b, 32-n tile); 16 row-groups x 5 rows; 16-c chunks.
// Phase 2 rowsum: block=(b, 32-n tile); 16 m-groups x 256 m.
// Phase 3 MFMA attention: block=(b, 32-m tile); 8 waves n-split.
__global__ void __launch_bounds__(512, 1)
fused2_kernel(const float* __restrict__ x,
              const float* __restrict__ wq, const float* __restrict__ bq,
              const float* __restrict__ wk, const float* __restrict__ bk,
              const float* __restrict__ wv, const float* __restrict__ bv,
              const float* __restrict__ gamma,
              unsigned* __restrict__ q4, unsigned* __restrict__ k4,
              unsigned* __restrict__ v16, float* __restrict__ lsv2,
              unsigned* __restrict__ bar, float* __restrict__ out) {
  __shared__ __align__(16) char smraw[73728];
  int t = threadIdx.x;
  int bid = blockIdx.x;
  int b = bid >> 7;

  // ---------------- Phase 1: QKV ----------------
  {
    float* wls  = (float*)smraw;     // [80][64] rows: 0-7 q, 8-15 k, 16-79 v
    float* bias = wls + 5120;        // [80]
    float* qkld = bias + 80;         // [16][32]
    int n0 = (bid & 127) << 5;
    int j = t & 31, rg = t >> 5;     // 16 groups x 5 rows

    {
      int i = t;                      // 512 threads cover 0..511
      wls[i] = (i < 512) ? wq[i] : 0.f;
    }
    for (int i = t + 512; i < 5120; i += 512)
      wls[i] = (i < 1024) ? wk[i - 512] : wv[i - 1024];
    if (t < 80) bias[t] = (t < 8) ? bq[t] : (t < 16 ? bk[t - 8] : bv[t - 16]);
    __syncthreads();

    float res[5];
    #pragma unroll
    for (int i = 0; i < 5; ++i) res[i] = bias[rg * 5 + i];

    const float* xb = x + ((b * 64) << 12) + n0 + j;
    // unroll 1 is load-bearing: full unroll hoists all 64 x-loads -> spill
    // (r5/r6 post-mortem: VGPR=256, ~37MB scratch traffic).
    #pragma unroll 1
    for (int c0 = 0; c0 < 64; c0 += 16) {
      float xr[16];
      #pragma unroll
      for (int cc = 0; cc < 16; ++cc) xr[cc] = xb[(c0 + cc) << 12];
      #pragma unroll
      for (int i = 0; i < 5; ++i) {
        const float4* wr4 = (const float4*)&wls[(rg * 5 + i) * 64 + c0];
        float acc = res[i];
        #pragma unroll
        for (int c4 = 0; c4 < 4; ++c4) {
          float4 w4 = wr4[c4];
          acc += w4.x * xr[4 * c4] + w4.y * xr[4 * c4 + 1]
               + w4.z * xr[4 * c4 + 2] + w4.w * xr[4 * c4 + 3];
        }
        res[i] = acc;
      }
    }

    #pragma unroll
    for (int i = 0; i < 5; ++i) {
      int r = rg * 5 + i;
      if (r < 16) {
        qkld[r * 32 + j] = res[i];
      } else {
        // f16 n-pair pack: partner col via xor1 swizzle (same branch: r uniform per rg)
        unsigned nbu = (unsigned)__builtin_amdgcn_ds_swizzle(
            __builtin_bit_cast(int, res[i]), 0x041F);
        if (!(j & 1)) {
          unsigned pr = pkf16(res[i], __builtin_bit_cast(float, nbu));
          v16[(((b << 6) + (r - 16)) << 11) + (n0 >> 1) + (j >> 1)] = pr;
        }
      }
    }
    __syncthreads();
    if (t < 64) {
      int jj = t & 31;
      bool isq = t < 32;
      int rb = isq ? 0 : 8;
      float sc = isq ? S2F : 1.0f;
      uint4 u;
      u.x = pkf16(sc * qkld[(rb + 0) * 32 + jj], sc * qkld[(rb + 1) * 32 + jj]);
      u.y = pkf16(sc * qkld[(rb + 2) * 32 + jj], sc * qkld[(rb + 3) * 32 + jj]);
      u.z = pkf16(sc * qkld[(rb + 4) * 32 + jj], sc * qkld[(rb + 5) * 32 + jj]);
      u.w = pkf16(sc * qkld[(rb + 6) * 32 + jj], sc * qkld[(rb + 7) * 32 + jj]);
      unsigned* dst = isq ? q4 : k4;
      *(uint4*)&dst[((b << 12) + n0 + jj) << 2] = u;
    }
  }
  gbar(bar, 256);

  // ---------------- Phase 2: rowsum ----------------
  {
    float* ps = (float*)smraw;   // [32][17]
    int nt0 = (bid & 127) << 5;
    int tn = t & 31, tg = t >> 5;    // 16 m-groups x 256 m
    uint4 qu = *(const uint4*)&q4[((b << 12) + nt0 + tn) << 2];
    h2 q0 = u2h(qu.x), q1 = u2h(qu.y), q2 = u2h(qu.z), q3 = u2h(qu.w);
    float acc = 0.f;
    int m0 = tg << 8;
    #pragma unroll 4
    for (int m = m0; m < m0 + 256; ++m) {
      uint4 ka = *(const uint4*)&k4[((b << 12) + m) << 2];
      float l = __builtin_amdgcn_fdot2(u2h(ka.x), q0, 0.f, false);
      l = __builtin_amdgcn_fdot2(u2h(ka.y), q1, l, false);
      l = __builtin_amdgcn_fdot2(u2h(ka.z), q2, l, false);
      l = __builtin_amdgcn_fdot2(u2h(ka.w), q3, l, false);
      acc += exp2f(l);
    }
    ps[tn * 17 + tg] = acc;
    __syncthreads();
    if (t < 32) {
      float s = 0.f;
      #pragma unroll
      for (int jj = 0; jj < 16; ++jj) s += ps[t * 17 + jj];
      lsv2[(b << 12) + nt0 + t] = -__log2f(s);
    }
  }
  gbar(bar + 1, 256);

  // ---------------- Phase 3: MFMA attention ----------------
  {
    float* red = (float*)smraw;  // [8][64][36]
    int m0 = (bid & 127) << 5;
    int w = t >> 6, l = t & 63;
    int L15 = l & 15, G = l >> 4;
    int permG = ((G & 1) << 1) | (G >> 1);
    bool even = (G & 1) == 0;

    uint4 bk2[2];
    #pragma unroll
    for (int mh = 0; mh < 2; ++mh) {
      if (l < 16) bk2[mh] = *(const uint4*)&k4[((b << 12) + m0 + mh * 16 + L15) << 2];
      else        bk2[mh] = make_uint4(0, 0, 0, 0);
    }
    f32x4 acc[2][4];
    #pragma unroll
    for (int mh = 0; mh < 2; ++mh)
      #pragma unroll
      for (int cf = 0; cf < 4; ++cf) acc[mh][cf] = (f32x4){0.f, 0.f, 0.f, 0.f};

    const float* svb = lsv2 + (b << 12);
    const unsigned* q4b = q4 + ((long)(b << 12) << 2);
    const unsigned* v16b = v16 + ((long)(b << 6) << 11);

    auto LOAD = [&](int step, half8& aq0, half8& aq1, f32x4& sv0, f32x4& sv1,
                    uint4* va) {
      int n0 = (w << 9) + (step << 5);
      aq0 = u4h8(*(const uint4*)&q4b[(n0 + L15) << 2]);
      aq1 = u4h8(*(const uint4*)&q4b[(n0 + 16 + L15) << 2]);
      sv0 = *(const f32x4*)&svb[n0 + (G << 2)];
      sv1 = *(const f32x4*)&svb[n0 + 16 + (G << 2)];
      #pragma unroll
      for (int cf = 0; cf < 4; ++cf)
        va[cf] = *(const uint4*)&v16b[(((cf << 4) + L15) << 11) + (n0 >> 1) + (permG << 2)];
    };
    auto COMPUTE = [&](half8 aq0, half8 aq1, f32x4 sv0, f32x4 sv1, const uint4* va) {
      #pragma unroll
      for (int mh = 0; mh < 2; ++mh) {
        f32x4 z = {0.f, 0.f, 0.f, 0.f};
        f32x4 d0 = __builtin_amdgcn_mfma_f32_16x16x32_f16(aq0, u4h8(bk2[mh]), z, 0, 0, 0);
        f32x4 d1 = __builtin_amdgcn_mfma_f32_16x16x32_f16(aq1, u4h8(bk2[mh]), z, 0, 0, 0);
        float p0[4], p1[4];
        #pragma unroll
        for (int r = 0; r < 4; ++r) {
          p0[r] = exp2f(d0[r] + sv0[r]);
          p1[r] = exp2f(d1[r] + sv1[r]);
        }
        unsigned x0 = pkf16(p0[0], p0[1]), x1 = pkf16(p0[2], p0[3]);
        unsigned y0 = pkf16(p1[0], p1[1]), y1 = pkf16(p1[2], p1[3]);
        unsigned snd0 = even ? y0 : x0;
        unsigned snd1 = even ? y1 : x1;
        unsigned r0 = (unsigned)__builtin_amdgcn_ds_swizzle((int)snd0, 0x401F);
        unsigned r1 = (unsigned)__builtin_amdgcn_ds_swizzle((int)snd1, 0x401F);
        uint4 Bu;
        Bu.x = even ? x0 : r0;
        Bu.y = even ? x1 : r1;
        Bu.z = even ? r0 : y0;
        Bu.w = even ? r1 : y1;
        half8 Bf = u4h8(Bu);
        #pragma unroll
        for (int cf = 0; cf < 4; ++cf)
          acc[mh][cf] = __builtin_amdgcn_mfma_f32_16x16x32_f16(u4h8(va[cf]), Bf, acc[mh][cf], 0, 0, 0);
      }
    };

    half8 aq0A, aq1A, aq0B, aq1B;
    f32x4 sv0A, sv1A, sv0B, sv1B;
    uint4 vaA[4], vaB[4];
    LOAD(0, aq0A, aq1A, sv0A, sv1A, vaA);
    #pragma unroll 1
    for (int step = 0; step < 16; step += 2) {
      LOAD(step + 1, aq0B, aq1B, sv0B, sv1B, vaB);
      COMPUTE(aq0A, aq1A, sv0A, sv1A, vaA);
      if (step < 14) LOAD(step + 2, aq0A, aq1A, sv0A, sv1A, vaA);
      COMPUTE(aq0B, aq1B, sv0B, sv1B, vaB);
    }

    #pragma unroll
    for (int mh = 0; mh < 2; ++mh)
      #pragma unroll
      for (int cf = 0; cf < 4; ++cf)
        *(f32x4*)&red[(((w << 6) + l) * 36) + (mh * 4 + cf) * 4] = acc[mh][cf];
    __syncthreads();
    int rl = t & 63, f = t >> 6;
    float g = gamma[0];
    f32x4 s = {0.f, 0.f, 0.f, 0.f};
    #pragma unroll
    for (int ww = 0; ww < 8; ++ww) s += *(const f32x4*)&red[(((ww << 6) + rl) * 36) + f * 4];
    int mh = f >> 2, cf = f & 3;
    int m = m0 + mh * 16 + (rl & 15);
    int cb = cf * 16 + ((rl >> 4) << 2);
    #pragma unroll
    for (int r = 0; r < 4; ++r) {
      int idx = (((b << 6) + cb + r) << 12) + m;
      out[idx] = g * s[r] + x[idx];
    }
  }
}

extern "C" void kernel_launch(void* const* d_in, const int* in_sizes, int n_in,
                              void* d_out, int out_size, void* d_ws, size_t ws_size,
                              hipStream_t stream) {
  const float* x     = (const float*)d_in[0];
  const float* wq    = (const float*)d_in[1];
  const float* bq    = (const float*)d_in[2];
  const float* wk    = (const float*)d_in[3];
  const float* bk    = (const float*)d_in[4];
  const float* wv    = (const float*)d_in[5];
  const float* bv    = (const float*)d_in[6];
  const float* gamma = (const float*)d_in[7];
  float* out = (float*)d_out;
  unsigned* wsu = (unsigned*)d_ws;
  unsigned* q4  = wsu;
  unsigned* k4  = wsu + 32768;
  unsigned* v16 = wsu + 65536;
  float*    lsv2 = (float*)(wsu + 327680);
  unsigned* bar = wsu + 335872;

  hipMemsetAsync(bar, 0, 8, stream);
  fused2_kernel<<<256, 512, 0, stream>>>(x, wq, bq, wk, bk, wv, bv, gamma,
                                         q4, k4, v16, lsv2, bar, out);
}

// Round 13
// 66.767 us; speedup vs baseline: 2.1480x; 2.1480x over previous
//
#include <hip/hip_runtime.h>

// q pre-scaled by SCALE*log2(e) at pack time -> logits are exp2-ready.
// Clamp(+-80) dropped: post-scale logits ~N(0,1); 80 sigma unreachable.
#define S2F (0.35355339059327373f * 1.4426950408889634f)

using h2 = decltype(__builtin_amdgcn_cvt_pkrtz(0.0f, 0.0f));
typedef _Float16 half8 __attribute__((ext_vector_type(8)));
typedef float f32x4 __attribute__((ext_vector_type(4)));

static __device__ __forceinline__ h2 u2h(unsigned u) { return __builtin_bit_cast(h2, u); }
static __device__ __forceinline__ unsigned pkf16(float a, float b) {
  return __builtin_bit_cast(unsigned, __builtin_amdgcn_cvt_pkrtz(a, b));
}
static __device__ __forceinline__ half8 u4h8(uint4 u) { return __builtin_bit_cast(half8, u); }

// ws layout (u32 offsets):
//   q4  [2][4096][4]u  @ 0       8 f16 o-values per n, PRE-SCALED by S2F
//   k4  [2][4096][4]u  @ 32768
//   v16 [2][64][2048]u @ 65536   f16 n-pairs
//   lsv2 [2][4096] f32 @ 327680  -log2(sum_m exp2(q'.k))

// qkv: grid 1280 = 2 b x 128 n-tiles(32) x 5 row-groups (r11, proven no-spill).
__global__ void __launch_bounds__(256, 4)
qkv_kernel(const float* __restrict__ x,
           const float* __restrict__ wq, const float* __restrict__ bq,
           const float* __restrict__ wk, const float* __restrict__ bk,
           const float* __restrict__ wv, const float* __restrict__ bv,
           unsigned* __restrict__ q4, unsigned* __restrict__ k4,
           unsigned* __restrict__ v16) {
  __shared__ float wls[16][64];
  __shared__ float bias16[16];
  __shared__ float qk_lds[16][32];
  int t = threadIdx.x;
  int bid = blockIdx.x;
  int b = bid / 640;
  int rem = bid - b * 640;
  int tile = rem / 5;
  int type = rem - tile * 5;
  int n0 = tile << 5;
  int j = t & 31, rg = t >> 5;     // 8 groups x 2 rows

  float* wflat = &wls[0][0];
  for (int i = t; i < 1024; i += 256) {
    float wv_;
    if (type == 0) wv_ = (i < 512) ? wq[i] : wk[i - 512];
    else           wv_ = wv[((type - 1) << 10) + i];
    wflat[i] = wv_;
  }
  if (t < 16)
    bias16[t] = (type == 0) ? ((t < 8) ? bq[t] : bk[t - 8])
                            : bv[((type - 1) << 4) + t];
  __syncthreads();

  float res0 = bias16[rg * 2], res1 = bias16[rg * 2 + 1];
  const float* xb = x + ((b * 64) << 12) + n0 + j;
  #pragma unroll 1
  for (int c0 = 0; c0 < 64; c0 += 16) {
    float xr[16];
    #pragma unroll
    for (int cc = 0; cc < 16; ++cc) xr[cc] = xb[(c0 + cc) << 12];
    const float4* w0 = (const float4*)&wls[rg * 2][c0];
    const float4* w1 = (const float4*)&wls[rg * 2 + 1][c0];
    #pragma unroll
    for (int c4 = 0; c4 < 4; ++c4) {
      float4 a = w0[c4], bb = w1[c4];
      res0 += a.x * xr[4*c4] + a.y * xr[4*c4+1] + a.z * xr[4*c4+2] + a.w * xr[4*c4+3];
      res1 += bb.x * xr[4*c4] + bb.y * xr[4*c4+1] + bb.z * xr[4*c4+2] + bb.w * xr[4*c4+3];
    }
  }

  if (type == 0) {
    qk_lds[rg * 2][j] = res0;
    qk_lds[rg * 2 + 1][j] = res1;
    __syncthreads();
    if (t < 64) {
      int jj = t & 31;
      bool isq = t < 32;
      int rb = isq ? 0 : 8;
      float sc = isq ? S2F : 1.0f;
      uint4 u;
      u.x = pkf16(sc * qk_lds[rb + 0][jj], sc * qk_lds[rb + 1][jj]);
      u.y = pkf16(sc * qk_lds[rb + 2][jj], sc * qk_lds[rb + 3][jj]);
      u.z = pkf16(sc * qk_lds[rb + 4][jj], sc * qk_lds[rb + 5][jj]);
      u.w = pkf16(sc * qk_lds[rb + 6][jj], sc * qk_lds[rb + 7][jj]);
      unsigned* dst = isq ? q4 : k4;
      *(uint4*)&dst[((b << 12) + n0 + jj) << 2] = u;
    }
  } else {
    int cbase = (type - 1) << 4;
    unsigned nb0 = (unsigned)__builtin_amdgcn_ds_swizzle(
        __builtin_bit_cast(int, res0), 0x041F);
    unsigned nb1 = (unsigned)__builtin_amdgcn_ds_swizzle(
        __builtin_bit_cast(int, res1), 0x041F);
    if (!(j & 1)) {
      int half = (n0 >> 1) + (j >> 1);
      v16[(((b << 6) + cbase + rg * 2) << 11) + half]     = pkf16(res0, __builtin_bit_cast(float, nb0));
      v16[(((b << 6) + cbase + rg * 2 + 1) << 11) + half] = pkf16(res1, __builtin_bit_cast(float, nb1));
    }
  }
}

// lsv2[b][n] = -log2( sum_m exp2(q'[n].k[m]) )
// 2048 blocks (b x 1024 4-n tiles), 256 thr, 8 blocks/CU -> 8 waves/SIMD.
__global__ void __launch_bounds__(256, 8)
rowsum_kernel(const unsigned* __restrict__ q4, const unsigned* __restrict__ k4,
              float* __restrict__ lsv2) {
  __shared__ float ps[4][65];
  int t = threadIdx.x;
  int b = blockIdx.x >> 10;
  int nt0 = (blockIdx.x & 1023) << 2;
  int tn = t & 3, tg = t >> 2;      // 64 m-groups x 64 m
  uint4 qu = *(const uint4*)&q4[((b << 12) + nt0 + tn) << 2];
  h2 q0 = u2h(qu.x), q1 = u2h(qu.y), q2 = u2h(qu.z), q3 = u2h(qu.w);
  float acc = 0.f;
  int m0 = tg << 6;
  #pragma unroll 4
  for (int m = m0; m < m0 + 64; ++m) {
    uint4 ka = *(const uint4*)&k4[((b << 12) + m) << 2];
    float l = __builtin_amdgcn_fdot2(u2h(ka.x), q0, 0.f, false);
    l = __builtin_amdgcn_fdot2(u2h(ka.y), q1, l, false);
    l = __builtin_amdgcn_fdot2(u2h(ka.z), q2, l, false);
    l = __builtin_amdgcn_fdot2(u2h(ka.w), q3, l, false);
    acc += exp2f(l);
  }
  ps[tn][tg] = acc;
  __syncthreads();
  if (t < 4) {
    float s = 0.f;
    #pragma unroll
    for (int j = 0; j < 64; ++j) s += ps[t][j];
    lsv2[(b << 12) + nt0 + t] = -__log2f(s);
  }
}

// MFMA attention: block = (b, 16-m tile), 8 waves n-split (512 n each).
// Grid 512, LDS 32KB, launch_bounds(512,2) -> 2 blocks/CU = 4 waves/SIMD.
__global__ void __launch_bounds__(512, 2)
attnout_kernel(const float* __restrict__ x, const unsigned* __restrict__ q4,
               const unsigned* __restrict__ k4, const unsigned* __restrict__ v16,
               const float* __restrict__ lsv2, const float* __restrict__ gamma,
               float* __restrict__ out) {
  __shared__ float red[8][64][16];
  int t = threadIdx.x;
  int b = blockIdx.x >> 8;
  int m0 = (blockIdx.x & 255) << 4;
  int w = t >> 6, l = t & 63;
  int L15 = l & 15, G = l >> 4;
  int permG = ((G & 1) << 1) | (G >> 1);
  bool even = (G & 1) == 0;

  uint4 bk2;
  if (l < 16) bk2 = *(const uint4*)&k4[((b << 12) + m0 + L15) << 2];
  else        bk2 = make_uint4(0, 0, 0, 0);
  f32x4 acc[4];
  #pragma unroll
  for (int cf = 0; cf < 4; ++cf) acc[cf] = (f32x4){0.f, 0.f, 0.f, 0.f};

  const float* svb = lsv2 + (b << 12);
  const unsigned* q4b = q4 + ((long)(b << 12) << 2);
  const unsigned* v16b = v16 + ((long)(b << 6) << 11);

  auto LOAD = [&](int step, half8& aq0, half8& aq1, f32x4& sv0, f32x4& sv1,
                  uint4* va) {
    int n0 = (w << 9) + (step << 5);
    aq0 = u4h8(*(const uint4*)&q4b[(n0 + L15) << 2]);
    aq1 = u4h8(*(const uint4*)&q4b[(n0 + 16 + L15) << 2]);
    sv0 = *(const f32x4*)&svb[n0 + (G << 2)];
    sv1 = *(const f32x4*)&svb[n0 + 16 + (G << 2)];
    #pragma unroll
    for (int cf = 0; cf < 4; ++cf)
      va[cf] = *(const uint4*)&v16b[(((cf << 4) + L15) << 11) + (n0 >> 1) + (permG << 2)];
  };
  auto COMPUTE = [&](half8 aq0, half8 aq1, f32x4 sv0, f32x4 sv1, const uint4* va) {
    f32x4 z = {0.f, 0.f, 0.f, 0.f};
    f32x4 d0 = __builtin_amdgcn_mfma_f32_16x16x32_f16(aq0, u4h8(bk2), z, 0, 0, 0);
    f32x4 d1 = __builtin_amdgcn_mfma_f32_16x16x32_f16(aq1, u4h8(bk2), z, 0, 0, 0);
    float p0[4], p1[4];
    #pragma unroll
    for (int r = 0; r < 4; ++r) {
      p0[r] = exp2f(d0[r] + sv0[r]);
      p1[r] = exp2f(d1[r] + sv1[r]);
    }
    unsigned x0 = pkf16(p0[0], p0[1]), x1 = pkf16(p0[2], p0[3]);
    unsigned y0 = pkf16(p1[0], p1[1]), y1 = pkf16(p1[2], p1[3]);
    unsigned snd0 = even ? y0 : x0;
    unsigned snd1 = even ? y1 : x1;
    unsigned r0 = (unsigned)__builtin_amdgcn_ds_swizzle((int)snd0, 0x401F);
    unsigned r1 = (unsigned)__builtin_amdgcn_ds_swizzle((int)snd1, 0x401F);
    uint4 Bu;
    Bu.x = even ? x0 : r0;
    Bu.y = even ? x1 : r1;
    Bu.z = even ? r0 : y0;
    Bu.w = even ? r1 : y1;
    half8 Bf = u4h8(Bu);
    #pragma unroll
    for (int cf = 0; cf < 4; ++cf)
      acc[cf] = __builtin_amdgcn_mfma_f32_16x16x32_f16(u4h8(va[cf]), Bf, acc[cf], 0, 0, 0);
  };

  half8 aq0A, aq1A, aq0B, aq1B;
  f32x4 sv0A, sv1A, sv0B, sv1B;
  uint4 vaA[4], vaB[4];
  LOAD(0, aq0A, aq1A, sv0A, sv1A, vaA);
  #pragma unroll 1
  for (int step = 0; step < 16; step += 2) {
    LOAD(step + 1, aq0B, aq1B, sv0B, sv1B, vaB);
    COMPUTE(aq0A, aq1A, sv0A, sv1A, vaA);
    if (step < 14) LOAD(step + 2, aq0A, aq1A, sv0A, sv1A, vaA);
    COMPUTE(aq0B, aq1B, sv0B, sv1B, vaB);
  }

  #pragma unroll
  for (int cf = 0; cf < 4; ++cf)
    *(f32x4*)&red[w][l][cf * 4] = acc[cf];
  __syncthreads();
  int rl = t & 63;
  int cf = (t >> 7) & 3;
  int rh = (t >> 6) & 1;
  float g = gamma[0];
  f32x4 s = {0.f, 0.f, 0.f, 0.f};
  #pragma unroll
  for (int ww = 0; ww < 8; ++ww) s += *(const f32x4*)&red[ww][rl][cf * 4];
  int m = m0 + (rl & 15);
  int cb = cf * 16 + ((rl >> 4) << 2);
  #pragma unroll
  for (int rr = 0; rr < 2; ++rr) {
    int r = rh * 2 + rr;
    int idx = (((b << 6) + cb + r) << 12) + m;
    out[idx] = g * s[r] + x[idx];
  }
}

extern "C" void kernel_launch(void* const* d_in, const int* in_sizes, int n_in,
                              void* d_out, int out_size, void* d_ws, size_t ws_size,
                              hipStream_t stream) {
  const float* x     = (const float*)d_in[0];
  const float* wq    = (const float*)d_in[1];
  const float* bq    = (const float*)d_in[2];
  const float* wk    = (const float*)d_in[3];
  const float* bk    = (const float*)d_in[4];
  const float* wv    = (const float*)d_in[5];
  const float* bv    = (const float*)d_in[6];
  const float* gamma = (const float*)d_in[7];
  float* out = (float*)d_out;
  unsigned* wsu = (unsigned*)d_ws;
  unsigned* q4  = wsu;
  unsigned* k4  = wsu + 32768;
  unsigned* v16 = wsu + 65536;
  float*    lsv2 = (float*)(wsu + 327680);

  qkv_kernel<<<1280, 256, 0, stream>>>(x, wq, bq, wk, bk, wv, bv, q4, k4, v16);
  rowsum_kernel<<<2048, 256, 0, stream>>>(q4, k4, lsv2);
  attnout_kernel<<<512, 512, 0, stream>>>(x, q4, k4, v16, lsv2, gamma, out);
}

// Round 14
// 58.431 us; speedup vs baseline: 2.4544x; 1.1427x over previous
//
#include <hip/hip_runtime.h>

// q pre-scaled by SCALE*log2(e) at pack time -> logits are exp2-ready.
// Clamp(+-80) dropped: post-scale logits ~N(0,1); 80 sigma unreachable.
#define S2F (0.35355339059327373f * 1.4426950408889634f)

using h2 = decltype(__builtin_amdgcn_cvt_pkrtz(0.0f, 0.0f));
typedef _Float16 half8 __attribute__((ext_vector_type(8)));
typedef float f32x4 __attribute__((ext_vector_type(4)));

static __device__ __forceinline__ h2 u2h(unsigned u) { return __builtin_bit_cast(h2, u); }
static __device__ __forceinline__ unsigned pkf16(float a, float b) {
  return __builtin_bit_cast(unsigned, __builtin_amdgcn_cvt_pkrtz(a, b));
}
static __device__ __forceinline__ half8 u4h8(uint4 u) { return __builtin_bit_cast(half8, u); }

// ws layout (u32 offsets):
//   q4  [2][4096][4]u  @ 0       8 f16 o-values per n, PRE-SCALED by S2F
//   k4  [2][4096][4]u  @ 32768
//   v16 [2][64][2048]u @ 65536   f16 n-pairs
//   lsv2 [2][4096] f32 @ 327680  -log2(sum_m exp2(q'.k))

// qkv: grid 1280 = 2 b x 128 n-tiles(32) x 5 row-groups (r11, proven no-spill).
__global__ void __launch_bounds__(256, 4)
qkv_kernel(const float* __restrict__ x,
           const float* __restrict__ wq, const float* __restrict__ bq,
           const float* __restrict__ wk, const float* __restrict__ bk,
           const float* __restrict__ wv, const float* __restrict__ bv,
           unsigned* __restrict__ q4, unsigned* __restrict__ k4,
           unsigned* __restrict__ v16) {
  __shared__ float wls[16][64];
  __shared__ float bias16[16];
  __shared__ float qk_lds[16][32];
  int t = threadIdx.x;
  int bid = blockIdx.x;
  int b = bid / 640;
  int rem = bid - b * 640;
  int tile = rem / 5;
  int type = rem - tile * 5;
  int n0 = tile << 5;
  int j = t & 31, rg = t >> 5;     // 8 groups x 2 rows

  float* wflat = &wls[0][0];
  for (int i = t; i < 1024; i += 256) {
    float wv_;
    if (type == 0) wv_ = (i < 512) ? wq[i] : wk[i - 512];
    else           wv_ = wv[((type - 1) << 10) + i];
    wflat[i] = wv_;
  }
  if (t < 16)
    bias16[t] = (type == 0) ? ((t < 8) ? bq[t] : bk[t - 8])
                            : bv[((type - 1) << 4) + t];
  __syncthreads();

  float res0 = bias16[rg * 2], res1 = bias16[rg * 2 + 1];
  const float* xb = x + ((b * 64) << 12) + n0 + j;
  #pragma unroll 1
  for (int c0 = 0; c0 < 64; c0 += 16) {
    float xr[16];
    #pragma unroll
    for (int cc = 0; cc < 16; ++cc) xr[cc] = xb[(c0 + cc) << 12];
    const float4* w0 = (const float4*)&wls[rg * 2][c0];
    const float4* w1 = (const float4*)&wls[rg * 2 + 1][c0];
    #pragma unroll
    for (int c4 = 0; c4 < 4; ++c4) {
      float4 a = w0[c4], bb = w1[c4];
      res0 += a.x * xr[4*c4] + a.y * xr[4*c4+1] + a.z * xr[4*c4+2] + a.w * xr[4*c4+3];
      res1 += bb.x * xr[4*c4] + bb.y * xr[4*c4+1] + bb.z * xr[4*c4+2] + bb.w * xr[4*c4+3];
    }
  }

  if (type == 0) {
    qk_lds[rg * 2][j] = res0;
    qk_lds[rg * 2 + 1][j] = res1;
    __syncthreads();
    if (t < 64) {
      int jj = t & 31;
      bool isq = t < 32;
      int rb = isq ? 0 : 8;
      float sc = isq ? S2F : 1.0f;
      uint4 u;
      u.x = pkf16(sc * qk_lds[rb + 0][jj], sc * qk_lds[rb + 1][jj]);
      u.y = pkf16(sc * qk_lds[rb + 2][jj], sc * qk_lds[rb + 3][jj]);
      u.z = pkf16(sc * qk_lds[rb + 4][jj], sc * qk_lds[rb + 5][jj]);
      u.w = pkf16(sc * qk_lds[rb + 6][jj], sc * qk_lds[rb + 7][jj]);
      unsigned* dst = isq ? q4 : k4;
      *(uint4*)&dst[((b << 12) + n0 + jj) << 2] = u;
    }
  } else {
    int cbase = (type - 1) << 4;
    unsigned nb0 = (unsigned)__builtin_amdgcn_ds_swizzle(
        __builtin_bit_cast(int, res0), 0x041F);
    unsigned nb1 = (unsigned)__builtin_amdgcn_ds_swizzle(
        __builtin_bit_cast(int, res1), 0x041F);
    if (!(j & 1)) {
      int half = (n0 >> 1) + (j >> 1);
      v16[(((b << 6) + cbase + rg * 2) << 11) + half]     = pkf16(res0, __builtin_bit_cast(float, nb0));
      v16[(((b << 6) + cbase + rg * 2 + 1) << 11) + half] = pkf16(res1, __builtin_bit_cast(float, nb1));
    }
  }
}

// lsv2[b][n] = -log2( sum_m exp2(q'[n].k[m]) )
// 2048 blocks (b x 1024 4-n tiles), 256 thr, 8 blocks/CU.
__global__ void __launch_bounds__(256, 8)
rowsum_kernel(const unsigned* __restrict__ q4, const unsigned* __restrict__ k4,
              float* __restrict__ lsv2) {
  __shared__ float ps[4][65];
  int t = threadIdx.x;
  int b = blockIdx.x >> 10;
  int nt0 = (blockIdx.x & 1023) << 2;
  int tn = t & 3, tg = t >> 2;      // 64 m-groups x 64 m
  uint4 qu = *(const uint4*)&q4[((b << 12) + nt0 + tn) << 2];
  h2 q0 = u2h(qu.x), q1 = u2h(qu.y), q2 = u2h(qu.z), q3 = u2h(qu.w);
  float acc = 0.f;
  int m0 = tg << 6;
  #pragma unroll 4
  for (int m = m0; m < m0 + 64; ++m) {
    uint4 ka = *(const uint4*)&k4[((b << 12) + m) << 2];
    float l = __builtin_amdgcn_fdot2(u2h(ka.x), q0, 0.f, false);
    l = __builtin_amdgcn_fdot2(u2h(ka.y), q1, l, false);
    l = __builtin_amdgcn_fdot2(u2h(ka.z), q2, l, false);
    l = __builtin_amdgcn_fdot2(u2h(ka.w), q3, l, false);
    acc += exp2f(l);
  }
  ps[tn][tg] = acc;
  __syncthreads();
  if (t < 4) {
    float s = 0.f;
    #pragma unroll
    for (int j = 0; j < 64; ++j) s += ps[t][j];
    lsv2[(b << 12) + nt0 + t] = -__log2f(s);
  }
}

// MFMA attention: block = (b, 32-m tile), 8 waves n-split (512 n each).
// red LDS halved to [4][64][36] (36KB) via two-round reduce -> 2 blocks/CU
// (r13 post-mortem: 16-m split doubled L2 traffic + bank conflicts; this
// raises occupancy at constant traffic; 36-stride is the conflict-clean one).
__global__ void __launch_bounds__(512, 4)
attnout_kernel(const float* __restrict__ x, const unsigned* __restrict__ q4,
               const unsigned* __restrict__ k4, const unsigned* __restrict__ v16,
               const float* __restrict__ lsv2, const float* __restrict__ gamma,
               float* __restrict__ out) {
  __shared__ float red[4][64][36];
  int t = threadIdx.x;
  int b = blockIdx.x >> 7;
  int m0 = (blockIdx.x & 127) << 5;
  int w = t >> 6, l = t & 63;
  int L15 = l & 15, G = l >> 4;
  int permG = ((G & 1) << 1) | (G >> 1);
  bool even = (G & 1) == 0;

  uint4 bk2[2];
  #pragma unroll
  for (int mh = 0; mh < 2; ++mh) {
    if (l < 16) bk2[mh] = *(const uint4*)&k4[((b << 12) + m0 + mh * 16 + L15) << 2];
    else        bk2[mh] = make_uint4(0, 0, 0, 0);
  }
  f32x4 acc[2][4];
  #pragma unroll
  for (int mh = 0; mh < 2; ++mh)
    #pragma unroll
    for (int cf = 0; cf < 4; ++cf) acc[mh][cf] = (f32x4){0.f, 0.f, 0.f, 0.f};

  const float* svb = lsv2 + (b << 12);
  const unsigned* q4b = q4 + ((long)(b << 12) << 2);
  const unsigned* v16b = v16 + ((long)(b << 6) << 11);

  auto LOAD = [&](int step, half8& aq0, half8& aq1, f32x4& sv0, f32x4& sv1,
                  uint4* va) {
    int n0 = (w << 9) + (step << 5);
    aq0 = u4h8(*(const uint4*)&q4b[(n0 + L15) << 2]);
    aq1 = u4h8(*(const uint4*)&q4b[(n0 + 16 + L15) << 2]);
    sv0 = *(const f32x4*)&svb[n0 + (G << 2)];
    sv1 = *(const f32x4*)&svb[n0 + 16 + (G << 2)];
    #pragma unroll
    for (int cf = 0; cf < 4; ++cf)
      va[cf] = *(const uint4*)&v16b[(((cf << 4) + L15) << 11) + (n0 >> 1) + (permG << 2)];
  };
  auto COMPUTE = [&](half8 aq0, half8 aq1, f32x4 sv0, f32x4 sv1, const uint4* va) {
    #pragma unroll
    for (int mh = 0; mh < 2; ++mh) {
      f32x4 z = {0.f, 0.f, 0.f, 0.f};
      f32x4 d0 = __builtin_amdgcn_mfma_f32_16x16x32_f16(aq0, u4h8(bk2[mh]), z, 0, 0, 0);
      f32x4 d1 = __builtin_amdgcn_mfma_f32_16x16x32_f16(aq1, u4h8(bk2[mh]), z, 0, 0, 0);
      float p0[4], p1[4];
      #pragma unroll
      for (int r = 0; r < 4; ++r) {
        p0[r] = exp2f(d0[r] + sv0[r]);
        p1[r] = exp2f(d1[r] + sv1[r]);
      }
      unsigned x0 = pkf16(p0[0], p0[1]), x1 = pkf16(p0[2], p0[3]);
      unsigned y0 = pkf16(p1[0], p1[1]), y1 = pkf16(p1[2], p1[3]);
      unsigned snd0 = even ? y0 : x0;
      unsigned snd1 = even ? y1 : x1;
      unsigned r0 = (unsigned)__builtin_amdgcn_ds_swizzle((int)snd0, 0x401F);
      unsigned r1 = (unsigned)__builtin_amdgcn_ds_swizzle((int)snd1, 0x401F);
      uint4 Bu;
      Bu.x = even ? x0 : r0;
      Bu.y = even ? x1 : r1;
      Bu.z = even ? r0 : y0;
      Bu.w = even ? r1 : y1;
      half8 Bf = u4h8(Bu);
      #pragma unroll
      for (int cf = 0; cf < 4; ++cf)
        acc[mh][cf] = __builtin_amdgcn_mfma_f32_16x16x32_f16(u4h8(va[cf]), Bf, acc[mh][cf], 0, 0, 0);
    }
  };

  half8 aq0A, aq1A, aq0B, aq1B;
  f32x4 sv0A, sv1A, sv0B, sv1B;
  uint4 vaA[4], vaB[4];
  LOAD(0, aq0A, aq1A, sv0A, sv1A, vaA);
  #pragma unroll 1
  for (int step = 0; step < 16; step += 2) {
    LOAD(step + 1, aq0B, aq1B, sv0B, sv1B, vaB);
    COMPUTE(aq0A, aq1A, sv0A, sv1A, vaA);
    if (step < 14) LOAD(step + 2, aq0A, aq1A, sv0A, sv1A, vaA);
    COMPUTE(aq0B, aq1B, sv0B, sv1B, vaB);
  }

  // two-round cross-wave reduction (waves 4-7 -> waves 0-3 -> epilogue over 4)
  if (w >= 4) {
    #pragma unroll
    for (int mh = 0; mh < 2; ++mh)
      #pragma unroll
      for (int cf = 0; cf < 4; ++cf)
        *(f32x4*)&red[w - 4][l][(mh * 4 + cf) * 4] = acc[mh][cf];
  }
  __syncthreads();
  if (w < 4) {
    #pragma unroll
    for (int mh = 0; mh < 2; ++mh)
      #pragma unroll
      for (int cf = 0; cf < 4; ++cf) {
        f32x4 o = *(const f32x4*)&red[w][l][(mh * 4 + cf) * 4];
        o += acc[mh][cf];
        *(f32x4*)&red[w][l][(mh * 4 + cf) * 4] = o;
      }
  }
  __syncthreads();
  int rl = t & 63, f = t >> 6;
  float g = gamma[0];
  f32x4 s = {0.f, 0.f, 0.f, 0.f};
  #pragma unroll
  for (int ww = 0; ww < 4; ++ww) s += *(const f32x4*)&red[ww][rl][f * 4];
  int mh = f >> 2, cf = f & 3;
  int m = m0 + mh * 16 + (rl & 15);
  int cb = cf * 16 + ((rl >> 4) << 2);
  #pragma unroll
  for (int r = 0; r < 4; ++r) {
    int idx = (((b << 6) + cb + r) << 12) + m;
    out[idx] = g * s[r] + x[idx];
  }
}

extern "C" void kernel_launch(void* const* d_in, const int* in_sizes, int n_in,
                              void* d_out, int out_size, void* d_ws, size_t ws_size,
                              hipStream_t stream) {
  const float* x     = (const float*)d_in[0];
  const float* wq    = (const float*)d_in[1];
  const float* bq    = (const float*)d_in[2];
  const float* wk    = (const float*)d_in[3];
  const float* bk    = (const float*)d_in[4];
  const float* wv    = (const float*)d_in[5];
  const float* bv    = (const float*)d_in[6];
  const float* gamma = (const float*)d_in[7];
  float* out = (float*)d_out;
  unsigned* wsu = (unsigned*)d_ws;
  unsigned* q4  = wsu;
  unsigned* k4  = wsu + 32768;
  unsigned* v16 = wsu + 65536;
  float*    lsv2 = (float*)(wsu + 327680);

  qkv_kernel<<<1280, 256, 0, stream>>>(x, wq, bq, wk, bk, wv, bv, q4, k4, v16);
  rowsum_kernel<<<2048, 256, 0, stream>>>(q4, k4, lsv2);
  attnout_kernel<<<256, 512, 0, stream>>>(x, q4, k4, v16, lsv2, gamma, out);
}

// Round 15
// 51.516 us; speedup vs baseline: 2.7838x; 1.1342x over previous
//
#include <hip/hip_runtime.h>

// q pre-scaled by SCALE*log2(e) at pack time -> logits are exp2-ready.
// Clamp(+-80) dropped: post-scale logits ~N(0,1); 80 sigma unreachable.
#define S2F (0.35355339059327373f * 1.4426950408889634f)

using h2 = decltype(__builtin_amdgcn_cvt_pkrtz(0.0f, 0.0f));
typedef _Float16 half8 __attribute__((ext_vector_type(8)));
typedef float f32x4 __attribute__((ext_vector_type(4)));

static __device__ __forceinline__ h2 u2h(unsigned u) { return __builtin_bit_cast(h2, u); }
static __device__ __forceinline__ unsigned pkf16(float a, float b) {
  return __builtin_bit_cast(unsigned, __builtin_amdgcn_cvt_pkrtz(a, b));
}
static __device__ __forceinline__ half8 u4h8(uint4 u) { return __builtin_bit_cast(half8, u); }

// ws layout (u32 offsets):
//   q4  [2][4096][4]u  @ 0       8 f16 o-values per n, PRE-SCALED by S2F
//   k4  [2][4096][4]u  @ 32768
//   v16 [2][64][2048]u @ 65536   f16 n-pairs
//   lsv2 [2][4096] f32 @ 327680  -log2(sum_m exp2(q'.k))

// qkv: grid 1280 = 2 b x 128 n-tiles(32) x 5 row-groups (r11, proven no-spill).
__global__ void __launch_bounds__(256, 4)
qkv_kernel(const float* __restrict__ x,
           const float* __restrict__ wq, const float* __restrict__ bq,
           const float* __restrict__ wk, const float* __restrict__ bk,
           const float* __restrict__ wv, const float* __restrict__ bv,
           unsigned* __restrict__ q4, unsigned* __restrict__ k4,
           unsigned* __restrict__ v16) {
  __shared__ float wls[16][64];
  __shared__ float bias16[16];
  __shared__ float qk_lds[16][32];
  int t = threadIdx.x;
  int bid = blockIdx.x;
  int b = bid / 640;
  int rem = bid - b * 640;
  int tile = rem / 5;
  int type = rem - tile * 5;
  int n0 = tile << 5;
  int j = t & 31, rg = t >> 5;     // 8 groups x 2 rows

  float* wflat = &wls[0][0];
  for (int i = t; i < 1024; i += 256) {
    float wv_;
    if (type == 0) wv_ = (i < 512) ? wq[i] : wk[i - 512];
    else           wv_ = wv[((type - 1) << 10) + i];
    wflat[i] = wv_;
  }
  if (t < 16)
    bias16[t] = (type == 0) ? ((t < 8) ? bq[t] : bk[t - 8])
                            : bv[((type - 1) << 4) + t];
  __syncthreads();

  float res0 = bias16[rg * 2], res1 = bias16[rg * 2 + 1];
  const float* xb = x + ((b * 64) << 12) + n0 + j;
  #pragma unroll 1
  for (int c0 = 0; c0 < 64; c0 += 16) {
    float xr[16];
    #pragma unroll
    for (int cc = 0; cc < 16; ++cc) xr[cc] = xb[(c0 + cc) << 12];
    const float4* w0 = (const float4*)&wls[rg * 2][c0];
    const float4* w1 = (const float4*)&wls[rg * 2 + 1][c0];
    #pragma unroll
    for (int c4 = 0; c4 < 4; ++c4) {
      float4 a = w0[c4], bb = w1[c4];
      res0 += a.x * xr[4*c4] + a.y * xr[4*c4+1] + a.z * xr[4*c4+2] + a.w * xr[4*c4+3];
      res1 += bb.x * xr[4*c4] + bb.y * xr[4*c4+1] + bb.z * xr[4*c4+2] + bb.w * xr[4*c4+3];
    }
  }

  if (type == 0) {
    qk_lds[rg * 2][j] = res0;
    qk_lds[rg * 2 + 1][j] = res1;
    __syncthreads();
    if (t < 64) {
      int jj = t & 31;
      bool isq = t < 32;
      int rb = isq ? 0 : 8;
      float sc = isq ? S2F : 1.0f;
      uint4 u;
      u.x = pkf16(sc * qk_lds[rb + 0][jj], sc * qk_lds[rb + 1][jj]);
      u.y = pkf16(sc * qk_lds[rb + 2][jj], sc * qk_lds[rb + 3][jj]);
      u.z = pkf16(sc * qk_lds[rb + 4][jj], sc * qk_lds[rb + 5][jj]);
      u.w = pkf16(sc * qk_lds[rb + 6][jj], sc * qk_lds[rb + 7][jj]);
      unsigned* dst = isq ? q4 : k4;
      *(uint4*)&dst[((b << 12) + n0 + jj) << 2] = u;
    }
  } else {
    int cbase = (type - 1) << 4;
    unsigned nb0 = (unsigned)__builtin_amdgcn_ds_swizzle(
        __builtin_bit_cast(int, res0), 0x041F);
    unsigned nb1 = (unsigned)__builtin_amdgcn_ds_swizzle(
        __builtin_bit_cast(int, res1), 0x041F);
    if (!(j & 1)) {
      int half = (n0 >> 1) + (j >> 1);
      v16[(((b << 6) + cbase + rg * 2) << 11) + half]     = pkf16(res0, __builtin_bit_cast(float, nb0));
      v16[(((b << 6) + cbase + rg * 2 + 1) << 11) + half] = pkf16(res1, __builtin_bit_cast(float, nb1));
    }
  }
}

// lsv2[b][n] = -log2( sum_m exp2(q'[n].k[m]) )  (r11 config)
__global__ void __launch_bounds__(256, 4)
rowsum_kernel(const unsigned* __restrict__ q4, const unsigned* __restrict__ k4,
              float* __restrict__ lsv2) {
  __shared__ float ps[8][33];
  int t = threadIdx.x;
  int b = blockIdx.x >> 9;
  int nt0 = (blockIdx.x & 511) << 3;
  int tn = t & 7, tg = t >> 3;      // 32 m-groups x 128 m
  uint4 qu = *(const uint4*)&q4[((b << 12) + nt0 + tn) << 2];
  h2 q0 = u2h(qu.x), q1 = u2h(qu.y), q2 = u2h(qu.z), q3 = u2h(qu.w);
  float acc = 0.f;
  int m0 = tg << 7;
  #pragma unroll 4
  for (int m = m0; m < m0 + 128; ++m) {
    uint4 ka = *(const uint4*)&k4[((b << 12) + m) << 2];
    float l = __builtin_amdgcn_fdot2(u2h(ka.x), q0, 0.f, false);
    l = __builtin_amdgcn_fdot2(u2h(ka.y), q1, l, false);
    l = __builtin_amdgcn_fdot2(u2h(ka.z), q2, l, false);
    l = __builtin_amdgcn_fdot2(u2h(ka.w), q3, l, false);
    acc += exp2f(l);
  }
  ps[tn][tg] = acc;
  __syncthreads();
  if (t < 8) {
    float s = 0.f;
    #pragma unroll
    for (int j = 0; j < 32; ++j) s += ps[t][j];
    lsv2[(b << 12) + nt0 + t] = -__log2f(s);
  }
}

// MFMA attention: block = (b, 32-m tile), 16 waves n-split (256 n each).
// 1024 thr -> 4 waves/SIMD at UNCHANGED per-block traffic (r13 lesson: never
// split m; r14 lesson: grid 256 can't exceed 1 block/CU, so widen the block).
// Prefetch va only (aq/sv inline) to stay under the 128-VGPR cap 1024-thread
// blocks impose. Two-round reduce into red[8][64][36] (72 KB, conflict-clean).
__global__ void __launch_bounds__(1024, 1)
attnout_kernel(const float* __restrict__ x, const unsigned* __restrict__ q4,
               const unsigned* __restrict__ k4, const unsigned* __restrict__ v16,
               const float* __restrict__ lsv2, const float* __restrict__ gamma,
               float* __restrict__ out) {
  __shared__ float red[8][64][36];
  int t = threadIdx.x;
  int b = blockIdx.x >> 7;
  int m0 = (blockIdx.x & 127) << 5;
  int w = t >> 6, l = t & 63;
  int L15 = l & 15, G = l >> 4;
  int permG = ((G & 1) << 1) | (G >> 1);
  bool even = (G & 1) == 0;

  uint4 bk2[2];
  #pragma unroll
  for (int mh = 0; mh < 2; ++mh) {
    if (l < 16) bk2[mh] = *(const uint4*)&k4[((b << 12) + m0 + mh * 16 + L15) << 2];
    else        bk2[mh] = make_uint4(0, 0, 0, 0);
  }
  f32x4 acc[2][4];
  #pragma unroll
  for (int mh = 0; mh < 2; ++mh)
    #pragma unroll
    for (int cf = 0; cf < 4; ++cf) acc[mh][cf] = (f32x4){0.f, 0.f, 0.f, 0.f};

  const float* svb = lsv2 + (b << 12);
  const unsigned* q4b = q4 + ((long)(b << 12) << 2);
  const unsigned* v16b = v16 + ((long)(b << 6) << 11);

  auto LOADVA = [&](int step, uint4* va) {
    int n0 = (w << 8) + (step << 5);
    #pragma unroll
    for (int cf = 0; cf < 4; ++cf)
      va[cf] = *(const uint4*)&v16b[(((cf << 4) + L15) << 11) + (n0 >> 1) + (permG << 2)];
  };
  auto COMPUTE = [&](int step, const uint4* va) {
    int n0 = (w << 8) + (step << 5);
    half8 aq0 = u4h8(*(const uint4*)&q4b[(n0 + L15) << 2]);
    half8 aq1 = u4h8(*(const uint4*)&q4b[(n0 + 16 + L15) << 2]);
    f32x4 sv0 = *(const f32x4*)&svb[n0 + (G << 2)];
    f32x4 sv1 = *(const f32x4*)&svb[n0 + 16 + (G << 2)];
    #pragma unroll
    for (int mh = 0; mh < 2; ++mh) {
      f32x4 z = {0.f, 0.f, 0.f, 0.f};
      f32x4 d0 = __builtin_amdgcn_mfma_f32_16x16x32_f16(aq0, u4h8(bk2[mh]), z, 0, 0, 0);
      f32x4 d1 = __builtin_amdgcn_mfma_f32_16x16x32_f16(aq1, u4h8(bk2[mh]), z, 0, 0, 0);
      float p0[4], p1[4];
      #pragma unroll
      for (int r = 0; r < 4; ++r) {
        p0[r] = exp2f(d0[r] + sv0[r]);
        p1[r] = exp2f(d1[r] + sv1[r]);
      }
      unsigned x0 = pkf16(p0[0], p0[1]), x1 = pkf16(p0[2], p0[3]);
      unsigned y0 = pkf16(p1[0], p1[1]), y1 = pkf16(p1[2], p1[3]);
      unsigned snd0 = even ? y0 : x0;
      unsigned snd1 = even ? y1 : x1;
      unsigned r0 = (unsigned)__builtin_amdgcn_ds_swizzle((int)snd0, 0x401F);
      unsigned r1 = (unsigned)__builtin_amdgcn_ds_swizzle((int)snd1, 0x401F);
      uint4 Bu;
      Bu.x = even ? x0 : r0;
      Bu.y = even ? x1 : r1;
      Bu.z = even ? r0 : y0;
      Bu.w = even ? r1 : y1;
      half8 Bf = u4h8(Bu);
      #pragma unroll
      for (int cf = 0; cf < 4; ++cf)
        acc[mh][cf] = __builtin_amdgcn_mfma_f32_16x16x32_f16(u4h8(va[cf]), Bf, acc[mh][cf], 0, 0, 0);
    }
  };

  uint4 vaA[4], vaB[4];
  LOADVA(0, vaA);
  #pragma unroll 1
  for (int step = 0; step < 8; step += 2) {
    LOADVA(step + 1, vaB);
    COMPUTE(step, vaA);
    if (step < 6) LOADVA(step + 2, vaA);
    COMPUTE(step + 1, vaB);
  }

  // two-round cross-wave reduction: waves 8-15 store, waves 0-7 add.
  if (w >= 8) {
    #pragma unroll
    for (int mh = 0; mh < 2; ++mh)
      #pragma unroll
      for (int cf = 0; cf < 4; ++cf)
        *(f32x4*)&red[w - 8][l][(mh * 4 + cf) * 4] = acc[mh][cf];
  }
  __syncthreads();
  if (w < 8) {
    #pragma unroll
    for (int mh = 0; mh < 2; ++mh)
      #pragma unroll
      for (int cf = 0; cf < 4; ++cf) {
        f32x4 o = *(const f32x4*)&red[w][l][(mh * 4 + cf) * 4];
        o += acc[mh][cf];
        *(f32x4*)&red[w][l][(mh * 4 + cf) * 4] = o;
      }
  }
  __syncthreads();
  int rl = t & 63;
  int fidx = (t >> 6) & 7;
  int rh = t >> 9;                 // 2 rows per thread
  float g = gamma[0];
  f32x4 s = {0.f, 0.f, 0.f, 0.f};
  #pragma unroll
  for (int ww = 0; ww < 8; ++ww) s += *(const f32x4*)&red[ww][rl][fidx * 4];
  int mh = fidx >> 2, cf = fidx & 3;
  int m = m0 + mh * 16 + (rl & 15);
  int cb = cf * 16 + ((rl >> 4) << 2);
  #pragma unroll
  for (int rr = 0; rr < 2; ++rr) {
    int r = rh * 2 + rr;
    int idx = (((b << 6) + cb + r) << 12) + m;
    out[idx] = g * s[r] + x[idx];
  }
}

extern "C" void kernel_launch(void* const* d_in, const int* in_sizes, int n_in,
                              void* d_out, int out_size, void* d_ws, size_t ws_size,
                              hipStream_t stream) {
  const float* x     = (const float*)d_in[0];
  const float* wq    = (const float*)d_in[1];
  const float* bq    = (const float*)d_in[2];
  const float* wk    = (const float*)d_in[3];
  const float* bk    = (const float*)d_in[4];
  const float* wv    = (const float*)d_in[5];
  const float* bv    = (const float*)d_in[6];
  const float* gamma = (const float*)d_in[7];
  float* out = (float*)d_out;
  unsigned* wsu = (unsigned*)d_ws;
  unsigned* q4  = wsu;
  unsigned* k4  = wsu + 32768;
  unsigned* v16 = wsu + 65536;
  float*    lsv2 = (float*)(wsu + 327680);

  qkv_kernel<<<1280, 256, 0, stream>>>(x, wq, bq, wk, bk, wv, bv, q4, k4, v16);
  rowsum_kernel<<<1024, 256, 0, stream>>>(q4, k4, lsv2);
  attnout_kernel<<<256, 1024, 0, stream>>>(x, q4, k4, v16, lsv2, gamma, out);
}

// Round 16
// 49.581 us; speedup vs baseline: 2.8925x; 1.0390x over previous
//
#include <hip/hip_runtime.h>

// q pre-scaled by SCALE*log2(e) at pack time -> logits are exp2-ready.
// Clamp(+-80) dropped: post-scale logits ~N(0,1); 80 sigma unreachable.
#define S2F (0.35355339059327373f * 1.4426950408889634f)

using h2 = decltype(__builtin_amdgcn_cvt_pkrtz(0.0f, 0.0f));
typedef _Float16 half8 __attribute__((ext_vector_type(8)));
typedef float f32x4 __attribute__((ext_vector_type(4)));

static __device__ __forceinline__ h2 u2h(unsigned u) { return __builtin_bit_cast(h2, u); }
static __device__ __forceinline__ unsigned pkf16(float a, float b) {
  return __builtin_bit_cast(unsigned, __builtin_amdgcn_cvt_pkrtz(a, b));
}
static __device__ __forceinline__ half8 u4h8(uint4 u) { return __builtin_bit_cast(half8, u); }

// ws layout (u32 offsets):
//   q4  [2][4096][4]u  @ 0       8 f16 o-values per n, PRE-SCALED by S2F
//   k4  [2][4096][4]u  @ 32768
//   v16 [2][64][2048]u @ 65536   f16 n-pairs, PI-PERMUTED within 32-n blocks
//   lsv2 [2][4096] f32 @ 327680  -log2(sum_m exp2(q'.k))
//
// PI-permutation: PV consumes n in order pi(G*8+j) = {G*4+j | 16+G*4+(j-4)}
// so each lane's P B-fragment is its OWN QK D-output (no cross-lane exchange).
// v16 uint-slot within each 16-uint (32-n) block: u' = ((u&6)<<1)|((u>>3)<<1)|(u&1).

// qkv: grid 1280 = 2 b x 128 n-tiles(32) x 5 row-groups (r11, proven no-spill).
__global__ void __launch_bounds__(256, 4)
qkv_kernel(const float* __restrict__ x,
           const float* __restrict__ wq, const float* __restrict__ bq,
           const float* __restrict__ wk, const float* __restrict__ bk,
           const float* __restrict__ wv, const float* __restrict__ bv,
           unsigned* __restrict__ q4, unsigned* __restrict__ k4,
           unsigned* __restrict__ v16) {
  __shared__ float wls[16][64];
  __shared__ float bias16[16];
  __shared__ float qk_lds[16][32];
  int t = threadIdx.x;
  int bid = blockIdx.x;
  int b = bid / 640;
  int rem = bid - b * 640;
  int tile = rem / 5;
  int type = rem - tile * 5;
  int n0 = tile << 5;
  int j = t & 31, rg = t >> 5;     // 8 groups x 2 rows

  float* wflat = &wls[0][0];
  for (int i = t; i < 1024; i += 256) {
    float wv_;
    if (type == 0) wv_ = (i < 512) ? wq[i] : wk[i - 512];
    else           wv_ = wv[((type - 1) << 10) + i];
    wflat[i] = wv_;
  }
  if (t < 16)
    bias16[t] = (type == 0) ? ((t < 8) ? bq[t] : bk[t - 8])
                            : bv[((type - 1) << 4) + t];
  __syncthreads();

  float res0 = bias16[rg * 2], res1 = bias16[rg * 2 + 1];
  const float* xb = x + ((b * 64) << 12) + n0 + j;
  #pragma unroll 1
  for (int c0 = 0; c0 < 64; c0 += 16) {
    float xr[16];
    #pragma unroll
    for (int cc = 0; cc < 16; ++cc) xr[cc] = xb[(c0 + cc) << 12];
    const float4* w0 = (const float4*)&wls[rg * 2][c0];
    const float4* w1 = (const float4*)&wls[rg * 2 + 1][c0];
    #pragma unroll
    for (int c4 = 0; c4 < 4; ++c4) {
      float4 a = w0[c4], bb = w1[c4];
      res0 += a.x * xr[4*c4] + a.y * xr[4*c4+1] + a.z * xr[4*c4+2] + a.w * xr[4*c4+3];
      res1 += bb.x * xr[4*c4] + bb.y * xr[4*c4+1] + bb.z * xr[4*c4+2] + bb.w * xr[4*c4+3];
    }
  }

  if (type == 0) {
    qk_lds[rg * 2][j] = res0;
    qk_lds[rg * 2 + 1][j] = res1;
    __syncthreads();
    if (t < 64) {
      int jj = t & 31;
      bool isq = t < 32;
      int rb = isq ? 0 : 8;
      float sc = isq ? S2F : 1.0f;
      uint4 u;
      u.x = pkf16(sc * qk_lds[rb + 0][jj], sc * qk_lds[rb + 1][jj]);
      u.y = pkf16(sc * qk_lds[rb + 2][jj], sc * qk_lds[rb + 3][jj]);
      u.z = pkf16(sc * qk_lds[rb + 4][jj], sc * qk_lds[rb + 5][jj]);
      u.w = pkf16(sc * qk_lds[rb + 6][jj], sc * qk_lds[rb + 7][jj]);
      unsigned* dst = isq ? q4 : k4;
      *(uint4*)&dst[((b << 12) + n0 + jj) << 2] = u;
    }
  } else {
    int cbase = (type - 1) << 4;
    unsigned nb0 = (unsigned)__builtin_amdgcn_ds_swizzle(
        __builtin_bit_cast(int, res0), 0x041F);
    unsigned nb1 = (unsigned)__builtin_amdgcn_ds_swizzle(
        __builtin_bit_cast(int, res1), 0x041F);
    if (!(j & 1)) {
      int u = j >> 1;                                        // natural pair slot
      int up = ((u & 6) << 1) | (((u >> 3) & 1) << 1) | (u & 1);  // pi-permuted slot
      int idx = (n0 >> 1) + up;
      v16[(((b << 6) + cbase + rg * 2) << 11) + idx]     = pkf16(res0, __builtin_bit_cast(float, nb0));
      v16[(((b << 6) + cbase + rg * 2 + 1) << 11) + idx] = pkf16(res1, __builtin_bit_cast(float, nb1));
    }
  }
}

// lsv2[b][n] = -log2( sum_m exp2(q'[n].k[m]) )  (r11 config)
__global__ void __launch_bounds__(256, 4)
rowsum_kernel(const unsigned* __restrict__ q4, const unsigned* __restrict__ k4,
              float* __restrict__ lsv2) {
  __shared__ float ps[8][33];
  int t = threadIdx.x;
  int b = blockIdx.x >> 9;
  int nt0 = (blockIdx.x & 511) << 3;
  int tn = t & 7, tg = t >> 3;      // 32 m-groups x 128 m
  uint4 qu = *(const uint4*)&q4[((b << 12) + nt0 + tn) << 2];
  h2 q0 = u2h(qu.x), q1 = u2h(qu.y), q2 = u2h(qu.z), q3 = u2h(qu.w);
  float acc = 0.f;
  int m0 = tg << 7;
  #pragma unroll 4
  for (int m = m0; m < m0 + 128; ++m) {
    uint4 ka = *(const uint4*)&k4[((b << 12) + m) << 2];
    float l = __builtin_amdgcn_fdot2(u2h(ka.x), q0, 0.f, false);
    l = __builtin_amdgcn_fdot2(u2h(ka.y), q1, l, false);
    l = __builtin_amdgcn_fdot2(u2h(ka.z), q2, l, false);
    l = __builtin_amdgcn_fdot2(u2h(ka.w), q3, l, false);
    acc += exp2f(l);
  }
  ps[tn][tg] = acc;
  __syncthreads();
  if (t < 8) {
    float s = 0.f;
    #pragma unroll
    for (int j = 0; j < 32; ++j) s += ps[t][j];
    lsv2[(b << 12) + nt0 + t] = -__log2f(s);
  }
}

// MFMA attention: block = (b, 32-m tile), 8 waves n-split (512 n each).
// SWIZZLE-FREE P path: each lane's PV B-frag = its own QK D-outputs via the
// pi n-permutation (va reads pi-permuted v16). Main loop has zero LDS ops.
__global__ void __launch_bounds__(512, 1)
attnout_kernel(const float* __restrict__ x, const unsigned* __restrict__ q4,
               const unsigned* __restrict__ k4, const unsigned* __restrict__ v16,
               const float* __restrict__ lsv2, const float* __restrict__ gamma,
               float* __restrict__ out) {
  __shared__ float red[8][64][36];
  int t = threadIdx.x;
  int b = blockIdx.x >> 7;
  int m0 = (blockIdx.x & 127) << 5;
  int w = t >> 6, l = t & 63;
  int L15 = l & 15, G = l >> 4;

  uint4 bk2[2];
  #pragma unroll
  for (int mh = 0; mh < 2; ++mh) {
    if (l < 16) bk2[mh] = *(const uint4*)&k4[((b << 12) + m0 + mh * 16 + L15) << 2];
    else        bk2[mh] = make_uint4(0, 0, 0, 0);
  }
  f32x4 acc[2][4];
  #pragma unroll
  for (int mh = 0; mh < 2; ++mh)
    #pragma unroll
    for (int cf = 0; cf < 4; ++cf) acc[mh][cf] = (f32x4){0.f, 0.f, 0.f, 0.f};

  const float* svb = lsv2 + (b << 12);
  const unsigned* q4b = q4 + ((long)(b << 12) << 2);
  const unsigned* v16b = v16 + ((long)(b << 6) << 11);

  auto LOAD = [&](int step, half8& aq0, half8& aq1, f32x4& sv0, f32x4& sv1,
                  uint4* va) {
    int n0 = (w << 9) + (step << 5);
    aq0 = u4h8(*(const uint4*)&q4b[(n0 + L15) << 2]);
    aq1 = u4h8(*(const uint4*)&q4b[(n0 + 16 + L15) << 2]);
    sv0 = *(const f32x4*)&svb[n0 + (G << 2)];
    sv1 = *(const f32x4*)&svb[n0 + 16 + (G << 2)];
    #pragma unroll
    for (int cf = 0; cf < 4; ++cf)
      va[cf] = *(const uint4*)&v16b[(((cf << 4) + L15) << 11) + (n0 >> 1) + (G << 2)];
  };
  auto COMPUTE = [&](half8 aq0, half8 aq1, f32x4 sv0, f32x4 sv1, const uint4* va) {
    #pragma unroll
    for (int mh = 0; mh < 2; ++mh) {
      f32x4 z = {0.f, 0.f, 0.f, 0.f};
      f32x4 d0 = __builtin_amdgcn_mfma_f32_16x16x32_f16(aq0, u4h8(bk2[mh]), z, 0, 0, 0);
      f32x4 d1 = __builtin_amdgcn_mfma_f32_16x16x32_f16(aq1, u4h8(bk2[mh]), z, 0, 0, 0);
      float p0[4], p1[4];
      #pragma unroll
      for (int r = 0; r < 4; ++r) {
        p0[r] = exp2f(d0[r] + sv0[r]);
        p1[r] = exp2f(d1[r] + sv1[r]);
      }
      // own-register B-frag: k-slots j=0..3 -> n=G*4+r, j=4..7 -> n=16+G*4+r
      uint4 Bu;
      Bu.x = pkf16(p0[0], p0[1]);
      Bu.y = pkf16(p0[2], p0[3]);
      Bu.z = pkf16(p1[0], p1[1]);
      Bu.w = pkf16(p1[2], p1[3]);
      half8 Bf = u4h8(Bu);
      #pragma unroll
      for (int cf = 0; cf < 4; ++cf)
        acc[mh][cf] = __builtin_amdgcn_mfma_f32_16x16x32_f16(u4h8(va[cf]), Bf, acc[mh][cf], 0, 0, 0);
    }
  };

  half8 aq0A, aq1A, aq0B, aq1B;
  f32x4 sv0A, sv1A, sv0B, sv1B;
  uint4 vaA[4], vaB[4];
  LOAD(0, aq0A, aq1A, sv0A, sv1A, vaA);
  #pragma unroll 1
  for (int step = 0; step < 16; step += 2) {
    LOAD(step + 1, aq0B, aq1B, sv0B, sv1B, vaB);
    COMPUTE(aq0A, aq1A, sv0A, sv1A, vaA);
    if (step < 14) LOAD(step + 2, aq0A, aq1A, sv0A, sv1A, vaA);
    COMPUTE(aq0B, aq1B, sv0B, sv1B, vaB);
  }

  #pragma unroll
  for (int mh = 0; mh < 2; ++mh)
    #pragma unroll
    for (int cf = 0; cf < 4; ++cf)
      *(f32x4*)&red[w][l][(mh * 4 + cf) * 4] = acc[mh][cf];
  __syncthreads();
  int rl = t & 63, f = t >> 6;
  float g = gamma[0];
  f32x4 s = {0.f, 0.f, 0.f, 0.f};
  #pragma unroll
  for (int ww = 0; ww < 8; ++ww) s += *(const f32x4*)&red[ww][rl][f * 4];
  int mh = f >> 2, cf = f & 3;
  int m = m0 + mh * 16 + (rl & 15);
  int cb = cf * 16 + ((rl >> 4) << 2);
  #pragma unroll
  for (int r = 0; r < 4; ++r) {
    int idx = (((b << 6) + cb + r) << 12) + m;
    out[idx] = g * s[r] + x[idx];
  }
}

extern "C" void kernel_launch(void* const* d_in, const int* in_sizes, int n_in,
                              void* d_out, int out_size, void* d_ws, size_t ws_size,
                              hipStream_t stream) {
  const float* x     = (const float*)d_in[0];
  const float* wq    = (const float*)d_in[1];
  const float* bq    = (const float*)d_in[2];
  const float* wk    = (const float*)d_in[3];
  const float* bk    = (const float*)d_in[4];
  const float* wv    = (const float*)d_in[5];
  const float* bv    = (const float*)d_in[6];
  const float* gamma = (const float*)d_in[7];
  float* out = (float*)d_out;
  unsigned* wsu = (unsigned*)d_ws;
  unsigned* q4  = wsu;
  unsigned* k4  = wsu + 32768;
  unsigned* v16 = wsu + 65536;
  float*    lsv2 = (float*)(wsu + 327680);

  qkv_kernel<<<1280, 256, 0, stream>>>(x, wq, bq, wk, bk, wv, bv, q4, k4, v16);
  rowsum_kernel<<<1024, 256, 0, stream>>>(q4, k4, lsv2);
  attnout_kernel<<<256, 512, 0, stream>>>(x, q4, k4, v16, lsv2, gamma, out);
}